// Round 3
// baseline (485.907 us; speedup 1.0000x reference)
//
#include <hip/hip_runtime.h>

#define DD 8
#define HH 56
#define WW 56
#define HWW (HH*WW)
#define NTOK (DD*HH*WW)      // 25088
#define BB 4
#define CC 128
#define NH 8
#define HD 16
#define MTOT (BB*NTOK)       // 100352

__device__ __forceinline__ unsigned short f2bf(float f){
    unsigned int u = __float_as_uint(f);
    u += 0x7FFFu + ((u>>16)&1u);
    return (unsigned short)(u>>16);
}
__device__ __forceinline__ float bf2f(unsigned short s){
    return __uint_as_float(((unsigned int)s)<<16);
}

// ---------------- Kernel A: fused QKV projection + q/k postprocess ----------------
// block: 256 threads, 64 rows x 384 cols. K=128 staged in 4 slices of 32.
__global__ __launch_bounds__(256)
void qkv_kernel(const float* __restrict__ x,
                const float* __restrict__ qw, const float* __restrict__ qb,
                const float* __restrict__ kvw, const float* __restrict__ kvb,
                const float* __restrict__ temp, const float* __restrict__ qemb,
                float* __restrict__ qbuf, float* __restrict__ kbuf,
                unsigned short* __restrict__ vbuf)
{
    __shared__ float xs[32*72];     // [k][row], stride 72 (16B aligned, conflict-light)
    __shared__ float wsl[32*388];   // [k][col], stride 388
    const int t = threadIdx.x;
    const int rowbase = blockIdx.x * 64;
    const int r0 = 4*(t>>4);
    const int c0 = 4*(t&15);

    float acc[4][24];
    #pragma unroll
    for (int cc=0; cc<6; ++cc){
        #pragma unroll
        for (int j=0;j<4;++j){
            int col = cc*64 + c0 + j;
            float b = (col<CC) ? qb[col] : kvb[col-CC];
            #pragma unroll
            for (int i=0;i<4;++i) acc[i][cc*4+j]=b;
        }
    }

    for (int ks=0; ks<4; ++ks){
        __syncthreads();
        #pragma unroll
        for (int i=0;i<2;++i){
            int id = 4*t + 1024*i;
            int row = id>>5, k0 = id&31;
            float4 xv = *reinterpret_cast<const float4*>(x + (size_t)(rowbase+row)*CC + ks*32 + k0);
            xs[(k0+0)*72+row]=xv.x; xs[(k0+1)*72+row]=xv.y;
            xs[(k0+2)*72+row]=xv.z; xs[(k0+3)*72+row]=xv.w;
        }
        #pragma unroll
        for (int i=0;i<12;++i){
            int id = 4*t + 1024*i;
            int c = id>>5, k0 = id&31;
            const float* wrow = (c<CC) ? (qw + (size_t)c*CC) : (kvw + (size_t)(c-CC)*CC);
            float4 wv = *reinterpret_cast<const float4*>(wrow + ks*32 + k0);
            wsl[(k0+0)*388+c]=wv.x; wsl[(k0+1)*388+c]=wv.y;
            wsl[(k0+2)*388+c]=wv.z; wsl[(k0+3)*388+c]=wv.w;
        }
        __syncthreads();
        #pragma unroll 4
        for (int k=0;k<32;++k){
            float4 xa = *reinterpret_cast<const float4*>(&xs[k*72 + r0]);
            float xr[4] = {xa.x, xa.y, xa.z, xa.w};
            #pragma unroll
            for (int cc=0;cc<6;++cc){
                float4 wb = *reinterpret_cast<const float4*>(&wsl[k*388 + cc*64 + c0]);
                float wr[4] = {wb.x,wb.y,wb.z,wb.w};
                #pragma unroll
                for (int i=0;i<4;++i){
                    #pragma unroll
                    for (int j=0;j<4;++j)
                        acc[i][cc*4+j] = fmaf(xr[i], wr[j], acc[i][cc*4+j]);
                }
            }
        }
    }

    // postprocess + store. chunk cc: cols cc*64.. ; sel 0=q,1=k,2=v
    #pragma unroll
    for (int cc=0; cc<6; ++cc){
        const int sel = cc>>1;
        const int colbase = (cc&1)*64 + c0;   // col within this output, 0..124, %4==0
        float vals[4][4];
        #pragma unroll
        for (int i=0;i<4;++i){
            #pragma unroll
            for (int j=0;j<4;++j) vals[i][j]=acc[i][cc*4+j];
        }

        if (sel<2){
            // l2norm over the head's 16 dims: 4-lane shuffle group (lanes 4a..4a+3)
            #pragma unroll
            for (int i=0;i<4;++i){
                float s = vals[i][0]*vals[i][0]+vals[i][1]*vals[i][1]
                        + vals[i][2]*vals[i][2]+vals[i][3]*vals[i][3];
                s += __shfl_xor(s,1);
                s += __shfl_xor(s,2);
                float inv = 1.0f/fmaxf(sqrtf(s),1e-12f);
                #pragma unroll
                for (int j=0;j<4;++j) vals[i][j]*=inv;
            }
        }
        if (sel==0){
            const int head = colbase>>4;
            const int d0 = colbase&15;
            float tm = temp[head];
            float sps = (tm>15.f)?tm:log1pf(__expf(tm));   // softplus(temperature)
            float qe[4];
            #pragma unroll
            for (int j=0;j<4;++j) qe[j]=qemb[head*HD + d0 + j];
            #pragma unroll
            for (int i=0;i<4;++i){
                int row = rowbase + r0 + i;
                int n = row % NTOK;
                int z = n / HWW; int rem = n - z*HWW;
                int y = rem / WW; int xx = rem - y*WW;
                int cnt = (3-(z==0)-(z==DD-1))*(3-(y==0)-(y==HH-1))*(3-(xx==0)-(xx==WW-1));
                float sc = logf((float)cnt) * sps;
                #pragma unroll
                for (int j=0;j<4;++j) vals[i][j]=(vals[i][j]+qe[j])*sc;
            }
        }
        #pragma unroll
        for (int i=0;i<4;++i){
            int row = rowbase + r0 + i;
            if (sel==0){
                *reinterpret_cast<float4*>(qbuf + (size_t)row*CC + colbase)
                    = make_float4(vals[i][0],vals[i][1],vals[i][2],vals[i][3]);
            } else if (sel==1){
                *reinterpret_cast<float4*>(kbuf + (size_t)row*CC + colbase)
                    = make_float4(vals[i][0],vals[i][1],vals[i][2],vals[i][3]);
            } else {
                *reinterpret_cast<ushort4*>(vbuf + (size_t)row*CC + colbase)
                    = make_ushort4(f2bf(vals[i][0]),f2bf(vals[i][1]),f2bf(vals[i][2]),f2bf(vals[i][3]));
            }
        }
    }
}

// ---------------- Kernel B: 27-neighbor attention ----------------
// 8 lanes per token (one per head); attn-out overwrites the token's own q slice (f32).
__global__ __launch_bounds__(256)
void attn_kernel(float* __restrict__ qa,
                 const float* __restrict__ kbuf,
                 const unsigned short* __restrict__ vbuf,
                 const float* __restrict__ rpb)
{
    const int t = threadIdx.x;
    const int tok = blockIdx.x*32 + (t>>3);
    const int h = t&7;
    const int n = tok % NTOK;
    const int z = n / HWW; const int rem = n - z*HWW;
    const int y = rem / WW; const int xx = rem - y*WW;
    const int tokbase = tok - n;   // b*NTOK

    float qf[16];
    {
        const float4* qp = reinterpret_cast<const float4*>(qa + (size_t)tok*CC + h*HD);
        float4 a=qp[0],b=qp[1],c=qp[2],d=qp[3];
        qf[0]=a.x;qf[1]=a.y;qf[2]=a.z;qf[3]=a.w;
        qf[4]=b.x;qf[5]=b.y;qf[6]=b.z;qf[7]=b.w;
        qf[8]=c.x;qf[9]=c.y;qf[10]=c.z;qf[11]=c.w;
        qf[12]=d.x;qf[13]=d.y;qf[14]=d.z;qf[15]=d.w;
    }

    float l[27];
    #pragma unroll
    for (int j=0;j<27;++j){
        const int dz=j/9, dy=(j/3)%3, dx=j%3;
        int z2=z+dz-1, y2=y+dy-1, x2=xx+dx-1;
        bool valid = ((unsigned)z2<DD) && ((unsigned)y2<HH) && ((unsigned)x2<WW);
        int row2 = valid ? (tokbase + z2*HWW + y2*WW + x2) : tok;
        const float4* kp = reinterpret_cast<const float4*>(kbuf + (size_t)row2*CC + h*HD);
        float4 ka=kp[0],kb=kp[1],kc=kp[2],kd=kp[3];
        float kk[16]={ka.x,ka.y,ka.z,ka.w, kb.x,kb.y,kb.z,kb.w,
                      kc.x,kc.y,kc.z,kc.w, kd.x,kd.y,kd.z,kd.w};
        float s = 0.f;
        #pragma unroll
        for (int d=0;d<16;++d) s = fmaf(qf[d],kk[d],s);
        l[j] = valid ? (s + rpb[h*27+j]) : -1e30f;
    }

    float m = l[0];
    #pragma unroll
    for (int j=1;j<27;++j) m = fmaxf(m,l[j]);
    float sum=0.f;
    #pragma unroll
    for (int j=0;j<27;++j){ float e=__expf(l[j]-m); l[j]=e; sum+=e; }
    float rs = 1.0f/sum;

    float o[16];
    #pragma unroll
    for (int d=0;d<16;++d) o[d]=0.f;
    #pragma unroll
    for (int j=0;j<27;++j){
        const int dz=j/9, dy=(j/3)%3, dx=j%3;
        int z2=z+dz-1, y2=y+dy-1, x2=xx+dx-1;
        bool valid = ((unsigned)z2<DD) && ((unsigned)y2<HH) && ((unsigned)x2<WW);
        int row2 = valid ? (tokbase + z2*HWW + y2*WW + x2) : tok;
        const uint4* vp = reinterpret_cast<const uint4*>(vbuf + (size_t)row2*CC + h*HD);
        uint4 va=vp[0], vb=vp[1];
        unsigned int vw[8]={va.x,va.y,va.z,va.w,vb.x,vb.y,vb.z,vb.w};
        float w = l[j];
        #pragma unroll
        for (int q2=0;q2<8;++q2){
            o[2*q2]   = fmaf(w, bf2f((unsigned short)(vw[q2]&0xffffu)), o[2*q2]);
            o[2*q2+1] = fmaf(w, bf2f((unsigned short)(vw[q2]>>16)),     o[2*q2+1]);
        }
    }
    #pragma unroll
    for (int d=0;d<16;++d) o[d]*=rs;
    float4* op = reinterpret_cast<float4*>(qa + (size_t)tok*CC + h*HD);
    op[0]=make_float4(o[0],o[1],o[2],o[3]);
    op[1]=make_float4(o[4],o[5],o[6],o[7]);
    op[2]=make_float4(o[8],o[9],o[10],o[11]);
    op[3]=make_float4(o[12],o[13],o[14],o[15]);
}

// ---------------- Kernel C: output projection ----------------
__global__ __launch_bounds__(256)
void proj_kernel(const float* __restrict__ ao, const float* __restrict__ pw,
                 const float* __restrict__ pb, float* __restrict__ out)
{
    __shared__ float xs[32*72];
    __shared__ float wsl[32*132];
    const int t = threadIdx.x;
    const int rowbase = blockIdx.x*64;
    const int r0 = 4*(t>>4);
    const int c0 = 8*(t&15);
    float acc[4][8];
    #pragma unroll
    for (int j=0;j<8;++j){
        float b=pb[c0+j];
        #pragma unroll
        for (int i=0;i<4;++i) acc[i][j]=b;
    }
    for (int ks=0;ks<4;++ks){
        __syncthreads();
        #pragma unroll
        for (int i=0;i<2;++i){
            int id=4*t+1024*i; int row=id>>5,k0=id&31;
            float4 xv = *reinterpret_cast<const float4*>(ao + (size_t)(rowbase+row)*CC + ks*32 + k0);
            xs[(k0+0)*72+row]=xv.x; xs[(k0+1)*72+row]=xv.y;
            xs[(k0+2)*72+row]=xv.z; xs[(k0+3)*72+row]=xv.w;
        }
        #pragma unroll
        for (int i=0;i<4;++i){
            int id=4*t+1024*i; int c=id>>5,k0=id&31;
            float4 wv = *reinterpret_cast<const float4*>(pw + (size_t)c*CC + ks*32 + k0);
            wsl[(k0+0)*132+c]=wv.x; wsl[(k0+1)*132+c]=wv.y;
            wsl[(k0+2)*132+c]=wv.z; wsl[(k0+3)*132+c]=wv.w;
        }
        __syncthreads();
        #pragma unroll 4
        for (int k=0;k<32;++k){
            float4 xa=*reinterpret_cast<const float4*>(&xs[k*72+r0]);
            float xr[4]={xa.x,xa.y,xa.z,xa.w};
            float4 w0=*reinterpret_cast<const float4*>(&wsl[k*132+c0]);
            float4 w1=*reinterpret_cast<const float4*>(&wsl[k*132+c0+4]);
            float wr[8]={w0.x,w0.y,w0.z,w0.w,w1.x,w1.y,w1.z,w1.w};
            #pragma unroll
            for (int i=0;i<4;++i){
                #pragma unroll
                for (int j=0;j<8;++j)
                    acc[i][j] = fmaf(xr[i], wr[j], acc[i][j]);
            }
        }
    }
    #pragma unroll
    for (int i=0;i<4;++i){
        int row=rowbase+r0+i;
        *reinterpret_cast<float4*>(out+(size_t)row*CC+c0)
            = make_float4(acc[i][0],acc[i][1],acc[i][2],acc[i][3]);
        *reinterpret_cast<float4*>(out+(size_t)row*CC+c0+4)
            = make_float4(acc[i][4],acc[i][5],acc[i][6],acc[i][7]);
    }
}

extern "C" void kernel_launch(void* const* d_in, const int* in_sizes, int n_in,
                              void* d_out, int out_size, void* d_ws, size_t ws_size,
                              hipStream_t stream)
{
    const float* x    = (const float*)d_in[0];
    const float* qw   = (const float*)d_in[1];
    const float* qb   = (const float*)d_in[2];
    const float* kvw  = (const float*)d_in[3];
    const float* kvb  = (const float*)d_in[4];
    const float* pw   = (const float*)d_in[5];
    const float* pb   = (const float*)d_in[6];
    const float* temp = (const float*)d_in[7];
    const float* qemb = (const float*)d_in[8];
    const float* rpb  = (const float*)d_in[9];

    float* qbuf = (float*)d_ws;                                   // q / attn-out, f32
    float* kbuf = qbuf + (size_t)MTOT*CC;                         // k, f32
    unsigned short* vbuf = (unsigned short*)(kbuf + (size_t)MTOT*CC); // v, bf16

    hipLaunchKernelGGL(qkv_kernel, dim3(MTOT/64), dim3(256), 0, stream,
                       x,qw,qb,kvw,kvb,temp,qemb,qbuf,kbuf,vbuf);
    hipLaunchKernelGGL(attn_kernel, dim3(MTOT/32), dim3(256), 0, stream,
                       qbuf,kbuf,vbuf,rpb);
    hipLaunchKernelGGL(proj_kernel, dim3(MTOT/64), dim3(256), 0, stream,
                       qbuf,pw,pb,(float*)d_out);
}